// Round 1
// baseline (644.946 us; speedup 1.0000x reference)
//
#include <hip/hip_runtime.h>

// MaxPoolAggregator: out[q, :] = max over s of features[nbrs[q,s], :]
// features: float32 [N_NODES, 128]   (512 B per row)
// nbrs:     int32   [N_QUERY, S]
// out:      float32 [N_QUERY, 128]
//
// Mapping: 32 lanes per query, each lane owns one float4 (16 B) of the 512 B
// row; a wave covers 2 queries, so one global_load_dwordx4 instruction pulls
// 2 full rows (1 KB) coalesced.
//
// This revision vs. previous (641 us):
//  - cooperative nbr fetch: lanes 0..9 of each 32-lane group load one index
//    (1 VMEM instr/group instead of 10/lane), broadcast via __shfl width=32.
//  - 32-bit voffset addressing (nbr*512 + g*16 < 2^31) -> saddr-form loads,
//    1 address VGPR per load instead of a 64-bit pair.
//  - __launch_bounds__(256, 8) pins VGPRs <= 64 -> 8 waves/SIMD for max
//    latency hiding on the random 512 B gathers.
//  - nontemporal store for the streaming 51 MB output (don't evict feature
//    lines from L2/L3; features are the only reused data).

typedef __attribute__((ext_vector_type(4))) float f32x4;

__global__ __launch_bounds__(256, 8) void maxpool10(
    const float* __restrict__ feats,   // 128 floats per row
    const int* __restrict__ nbrs,
    float* __restrict__ out,
    int n_query)
{
    int idx = blockIdx.x * blockDim.x + threadIdx.x;
    int q = idx >> 5;          // query id (32 lanes per query)
    int g = idx & 31;          // float4 chunk within the 128-float row
    if (q >= n_query) return;

    // One VMEM instr per 32-lane group: lanes 0..9 fetch the 10 indices.
    int nbr_l = 0;
    if (g < 10) nbr_l = nbrs[(long)q * 10 + g];

    const char* fb = (const char*)feats;
    const unsigned goff = (unsigned)g * 16u;

    f32x4 m;
    {
        unsigned off = (unsigned)__shfl(nbr_l, 0, 32) * 512u + goff;
        m = *(const f32x4*)(fb + off);
    }
    #pragma unroll
    for (int s = 1; s < 10; ++s) {
        unsigned off = (unsigned)__shfl(nbr_l, s, 32) * 512u + goff;
        f32x4 v = *(const f32x4*)(fb + off);
        m[0] = fmaxf(m[0], v[0]);
        m[1] = fmaxf(m[1], v[1]);
        m[2] = fmaxf(m[2], v[2]);
        m[3] = fmaxf(m[3], v[3]);
    }

    f32x4* op = (f32x4*)(out + (size_t)q * 128) + g;
    __builtin_nontemporal_store(m, op);
}

// Generic fallback for num_sample != 10 (correctness path, not perf-tuned).
__global__ __launch_bounds__(256) void maxpool_generic(
    const float* __restrict__ feats,
    const int* __restrict__ nbrs,
    float* __restrict__ out,
    int n_query, int num_sample)
{
    int idx = blockIdx.x * blockDim.x + threadIdx.x;
    int q = idx >> 5;
    int g = idx & 31;
    if (q >= n_query) return;

    const long base = (long)q * num_sample;

    f32x4 m;
    {
        int nbr = nbrs[base];
        m = *((const f32x4*)(feats + (size_t)nbr * 128) + g);
    }
    for (int s = 1; s < num_sample; ++s) {
        int nbr = nbrs[base + s];
        f32x4 v = *((const f32x4*)(feats + (size_t)nbr * 128) + g);
        m[0] = fmaxf(m[0], v[0]);
        m[1] = fmaxf(m[1], v[1]);
        m[2] = fmaxf(m[2], v[2]);
        m[3] = fmaxf(m[3], v[3]);
    }

    *((f32x4*)(out + (size_t)q * 128) + g) = m;
}

extern "C" void kernel_launch(void* const* d_in, const int* in_sizes, int n_in,
                              void* d_out, int out_size, void* d_ws, size_t ws_size,
                              hipStream_t stream) {
    const float* feats = (const float*)d_in[0];
    const int*   nbrs  = (const int*)d_in[1];
    float*       out   = (float*)d_out;

    const int D = 128;                           // feature dim per reference
    int n_query = out_size / D;
    int num_sample = (n_query > 0) ? (in_sizes[1] / n_query) : 1;

    int total = n_query * 32;                    // 32 threads per query
    int blocks = (total + 255) / 256;

    if (num_sample == 10) {
        maxpool10<<<blocks, 256, 0, stream>>>(feats, nbrs, out, n_query);
    } else {
        maxpool_generic<<<blocks, 256, 0, stream>>>(feats, nbrs, out, n_query, num_sample);
    }
}